// Round 3
// baseline (165.361 us; speedup 1.0000x reference)
//
#include <hip/hip_runtime.h>
#include <float.h>

#define CC 256
#define HH 200
#define WW 320
#define HW (HH * WW)
#define MM 14
#define SPAN 148          // padded LDS row length (floats), multiple of 4, %32=20
#define NCH 8             // channels staged per round
#define CG 2              // channel-group blocks per (roi, bin-row)
#define CPB (CC / CG)     // 128 channels per block
#define ROUNDS (CPB / NCH)  // 16

typedef __attribute__((address_space(1))) const float GF;
typedef __attribute__((address_space(3))) float LF;

__global__ void roi_init(float* __restrict__ binmax) {
    int t = blockIdx.x * blockDim.x + threadIdx.x;
    if (t < MM * MM) binmax[t] = -FLT_MAX;
}

__device__ inline void atomicMaxF(float* addr, float val) {
    // Ordered-int trick: valid for finite floats. Positive patterns (int max)
    // and negative patterns (uint min) compose correctly from -FLT_MAX init.
    if (val >= 0.0f) {
        atomicMax((int*)addr, __float_as_int(val));
    } else {
        atomicMin((unsigned int*)addr, __float_as_uint(val));
    }
}

__global__ __launch_bounds__(256, 4) void roi_reduce(
    const float* __restrict__ feature,
    const float* __restrict__ rois,
    float* __restrict__ binmax)
{
    __shared__ float tile[2][NCH][4][SPAN];  // 37.9 KB, double-buffered
    __shared__ float pmax[4][MM];

    const int bid = blockIdx.x;
    const int cg  = bid & (CG - 1);
    const int rm  = bid >> 1;        // CG == 2
    const int m   = rm % MM;
    const int r   = rm / MM;
    const int tid  = threadIdx.x;
    const int w    = tid >> 6;       // wave id 0..3
    const int lane = tid & 63;
    const int cbase = cg * CPB;

    const float ry1 = rois[r * 4 + 0];
    const float rx1 = rois[r * 4 + 1];
    const float ry2 = rois[r * 4 + 2];
    const float rx2 = rois[r * 4 + 3];
    const float sh = (ry2 - ry1) * (1.0f / 14.0f);
    const float sw = (rx2 - rx1) * (1.0f / 14.0f);
    const float f13 = 1.0f / 3.0f, f23 = 2.0f / 3.0f;

    // Two y sample coords for this bin-row m (reference clamp semantics).
    const float yA = ry1 + sh * (float)m + sh * f13;
    const float yB = ry1 + sh * (float)m + sh * f23;
    const int y1A = min(max((int)floorf(yA), 0), HH - 1);
    const int y2A = min(max((int)floorf(yA) + 1, 0), HH - 1);
    const int y1B = min(max((int)floorf(yB), 0), HH - 1);
    const int y2B = min(max((int)floorf(yB) + 1, 0), HH - 1);
    const float wyloA = yA - (float)y1A, wyhiA = (float)y2A - yA;
    const float wyloB = yB - (float)y1B, wyhiB = (float)y2B - yB;

    // Column window covering all 28 x-sample corners; align base down to x4
    // so global_load_lds dwordx4 addresses are 16B-aligned.
    const float xmin = rx1 + sw * f13;
    const float xmax = rx1 + sw * 13.0f + sw * f23;
    const int xlo = (min(max((int)floorf(xmin), 0), WW - 1)) & ~3;
    const int xhi = min(max((int)floorf(xmax) + 1, 0), WW - 1);
    int span = xhi - xlo + 1;              // <= 147 for graded inputs
    if (span > SPAN) span = SPAN;
    const int nlanes = (span + 3) >> 2;    // lanes needed for width-16 DMA

    // Staging: wave w owns feature row w of {y1A, y2A, y1B, y2B}.
    const int myrow = (w == 0) ? y1A : (w == 1) ? y2A : (w == 2) ? y1B : y2B;
    // Per-lane global pointer (16B per lane). May read <=12B past the row's
    // needed span (and, for ch=255,row=199 only, past the tensor) — page-safe,
    // lands in LDS pad columns that are never read.
    const float* gbase = feature + (cbase * HW + myrow * WW + xlo) + lane * 4;

    // Compute mapping: lane = n*4 + j*2 + i, lanes 0..55 active.
    const bool active = lane < 56;
    const int n = lane >> 2;
    const int j = (lane >> 1) & 1;
    const int i = lane & 1;

    float wxlo = 0.f, wxhi = 0.f, wylo = 0.f, wyhi = 0.f;
    int c0 = 0, ra = 0;
    if (active) {
        float x = rx1 + sw * (float)n + sw * (j ? f23 : f13);
        int x1c = min(max((int)floorf(x), 0), WW - 1);
        int x2c = min(max((int)floorf(x) + 1, 0), WW - 1);
        wxlo = x - (float)x1c;
        wxhi = (float)x2c - x;
        c0 = min(max(x1c - xlo, 0), SPAN - 2);  // c1 == c0+1 (no clamp for graded inputs)
        if (i == 0) { ra = 0; wylo = wyloA; wyhi = wyhiA; }
        else        { ra = 2; wylo = wyloB; wyhi = wyhiB; }
    }

    // Async stage of round rd into buffer b: 8 channels, this wave's row.
    auto stage = [&](int rd, int b) {
        const float* g = gbase + rd * (NCH * HW);
        if (lane < nlanes) {
            #pragma unroll
            for (int ch = 0; ch < NCH; ++ch) {
                __builtin_amdgcn_global_load_lds(
                    (GF*)(g + ch * HW), (LF*)&tile[b][ch][w][0], 16, 0, 0);
            }
        }
    };

    stage(0, 0);
    float lmax = -FLT_MAX;
    int buf = 0;

    for (int rd = 0; rd < ROUNDS; ++rd) {
        __syncthreads();   // drains own-wave vmcnt -> tile[buf] ready; prev readers done
        if (rd + 1 < ROUNDS) stage(rd + 1, buf ^ 1);
        if (active) {
            #pragma unroll
            for (int q = 0; q < 2; ++q) {
                const float* rp = &tile[buf][w * 2 + q][ra][0];
                float v11 = rp[c0];
                float v12 = rp[c0 + 1];
                float v21 = rp[SPAN + c0];      // rb = ra+1
                float v22 = rp[SPAN + c0 + 1];
                float p  = v11 * wxhi + v12 * wxlo;
                float qq = v21 * wxhi + v22 * wxlo;
                lmax = fmaxf(lmax, p * wyhi + qq * wylo);
            }
        }
        buf ^= 1;
    }

    // Reduce the 4 sample points (j,i) per bin n within the wave.
    float v = lmax;
    v = fmaxf(v, __shfl_xor(v, 1));
    v = fmaxf(v, __shfl_xor(v, 2));
    if (active && (lane & 3) == 0) pmax[w][n] = v;
    __syncthreads();
    if (tid < MM) {
        float vv = fmaxf(fmaxf(pmax[0][tid], pmax[1][tid]),
                         fmaxf(pmax[2][tid], pmax[3][tid]));
        atomicMaxF(&binmax[m * MM + tid], vv);
    }
}

__global__ __launch_bounds__(256) void roi_bcast(
    const float* __restrict__ binmax, float4* __restrict__ out, int total4)
{
    __shared__ float4 b4[49];  // 196 floats = 49 float4, aligned with bin period
    int t = threadIdx.x;
    if (t < 49) b4[t] = ((const float4*)binmax)[t];
    __syncthreads();
    int idx = blockIdx.x * 256 + t;
    if (idx < total4) out[idx] = b4[idx % 49];
}

extern "C" void kernel_launch(void* const* d_in, const int* in_sizes, int n_in,
                              void* d_out, int out_size, void* d_ws, size_t ws_size,
                              hipStream_t stream) {
    const float* feature = (const float*)d_in[0];
    const float* rois    = (const float*)d_in[1];
    float* binmax = (float*)d_ws;
    float* out    = (float*)d_out;

    const int R = in_sizes[1] / 4;

    roi_init<<<1, 256, 0, stream>>>(binmax);
    roi_reduce<<<R * MM * CG, 256, 0, stream>>>(feature, rois, binmax);

    const int total4 = out_size / 4;
    roi_bcast<<<(total4 + 255) / 256, 256, 0, stream>>>(binmax, (float4*)out, total4);
}

// Round 4
// 164.244 us; speedup vs baseline: 1.0068x; 1.0068x over previous
//
#include <hip/hip_runtime.h>
#include <float.h>

#define CC 256
#define HH 200
#define WW 320
#define HW (HH * WW)
#define MM 14
#define SPAN 152          // padded LDS row length (floats): xlo align-down +3 headroom
#define NB 2              // LDS buffers per wave (double buffer)
#define CPW 64            // channels per wave (CC / 4 waves)

typedef __attribute__((address_space(1))) const float GF;
typedef __attribute__((address_space(3))) float LF;

__global__ void roi_init(float* __restrict__ binmax) {
    int t = blockIdx.x * blockDim.x + threadIdx.x;
    if (t < MM * MM) binmax[t] = -FLT_MAX;
}

__device__ inline void atomicMaxF(float* addr, float val) {
    // Ordered-int trick: valid for finite floats starting from -FLT_MAX init.
    if (val >= 0.0f) {
        atomicMax((int*)addr, __float_as_int(val));
    } else {
        atomicMin((unsigned int*)addr, __float_as_uint(val));
    }
}

// One block per (roi, bin-row m). Each wave owns channels {w, w+4, w+8, ...}
// end-to-end: it DMA-stages its own 4 feature rows per channel and computes
// them itself. NO __syncthreads in the main loop — per-wave pipeline with
// explicit s_waitcnt vmcnt(4) (stage ch t+2 while computing ch t).
__global__ __launch_bounds__(256) void roi_reduce(
    const float* __restrict__ feature,
    const float* __restrict__ rois,
    float* __restrict__ binmax)
{
    __shared__ float tile[4][NB][4][SPAN];  // [wave][buf][row][col] = 19,456 B
    __shared__ float pmax[4][MM];

    const int bid = blockIdx.x;
    const int m   = bid % MM;
    const int r   = bid / MM;
    const int tid  = threadIdx.x;
    const int w    = tid >> 6;
    const int lane = tid & 63;

    const float ry1 = rois[r * 4 + 0];
    const float rx1 = rois[r * 4 + 1];
    const float ry2 = rois[r * 4 + 2];
    const float rx2 = rois[r * 4 + 3];
    const float sh = (ry2 - ry1) * (1.0f / 14.0f);
    const float sw = (rx2 - rx1) * (1.0f / 14.0f);
    const float f13 = 1.0f / 3.0f, f23 = 2.0f / 3.0f;

    // Two y sample coords for this bin-row m (reference clamp semantics).
    const float yA = ry1 + sh * (float)m + sh * f13;
    const float yB = ry1 + sh * (float)m + sh * f23;
    const int y1A = min(max((int)floorf(yA), 0), HH - 1);
    const int y2A = min(max((int)floorf(yA) + 1, 0), HH - 1);
    const int y1B = min(max((int)floorf(yB), 0), HH - 1);
    const int y2B = min(max((int)floorf(yB) + 1, 0), HH - 1);
    const float wyloA = yA - (float)y1A, wyhiA = (float)y2A - yA;
    const float wyloB = yB - (float)y1B, wyhiB = (float)y2B - yB;

    // Column window covering all 28 x-sample corners; align base down to x4
    // so global_load_lds dwordx4 addresses are 16B-aligned.
    const float xmin = rx1 + sw * f13;
    const float xmax = rx1 + sw * 13.0f + sw * f23;
    const int xlo = (min(max((int)floorf(xmin), 0), WW - 1)) & ~3;
    const int xhi = min(max((int)floorf(xmax) + 1, 0), WW - 1);
    int span = xhi - xlo + 1;
    if (span > SPAN) span = SPAN;
    const int nlanes = (span + 3) >> 2;    // lanes for width-16 DMA, <= 38

    // Per-lane global pointers for this wave's 4 rows, channel = w (round 0).
    // Channel stride per round is 4*HW. Tail lanes may read <=12B past the
    // row's span (pad cols, never read) — page-safe.
    const int rows[4] = { y1A, y2A, y1B, y2B };
    const float* bp0 = feature + (w * HW + rows[0] * WW + xlo) + lane * 4;
    const float* bp1 = feature + (w * HW + rows[1] * WW + xlo) + lane * 4;
    const float* bp2 = feature + (w * HW + rows[2] * WW + xlo) + lane * 4;
    const float* bp3 = feature + (w * HW + rows[3] * WW + xlo) + lane * 4;

    // Compute mapping: lane = n*4 + j*2 + i, lanes 0..55 active.
    const bool active = lane < 56;
    const int n = lane >> 2;
    const int j = (lane >> 1) & 1;
    const int i = lane & 1;

    float wxlo = 0.f, wxhi = 0.f, wylo = 0.f, wyhi = 0.f;
    int o_lane = 0;
    if (active) {
        float x = rx1 + sw * (float)n + sw * (j ? f23 : f13);
        int x1c = min(max((int)floorf(x), 0), WW - 1);
        int x2c = min(max((int)floorf(x) + 1, 0), WW - 1);
        wxlo = x - (float)x1c;
        wxhi = (float)x2c - x;
        int c0 = min(max(x1c - xlo, 0), SPAN - 2);
        int ra = i * 2;                    // rows (0,1) for sample A, (2,3) for B
        o_lane = ra * SPAN + c0;
        if (i == 0) { wylo = wyloA; wyhi = wyhiA; }
        else        { wylo = wyloB; wyhi = wyhiB; }
    }
    const float* rp0 = &tile[w][0][0][0] + o_lane;
    const float* rp1 = &tile[w][1][0][0] + o_lane;

    auto stage = [&](int t, int b) {
        const int co = t * 4 * HW;         // channel offset (floats)
        if (lane < nlanes) {
            __builtin_amdgcn_global_load_lds((GF*)(bp0 + co), (LF*)&tile[w][b][0][0], 16, 0, 0);
            __builtin_amdgcn_global_load_lds((GF*)(bp1 + co), (LF*)&tile[w][b][1][0], 16, 0, 0);
            __builtin_amdgcn_global_load_lds((GF*)(bp2 + co), (LF*)&tile[w][b][2][0], 16, 0, 0);
            __builtin_amdgcn_global_load_lds((GF*)(bp3 + co), (LF*)&tile[w][b][3][0], 16, 0, 0);
        }
    };

    float lmax = -FLT_MAX;
    auto compute = [&](const float* rp) {
        float v11 = rp[0];
        float v12 = rp[1];
        float v21 = rp[SPAN];
        float v22 = rp[SPAN + 1];
        float p  = v11 * wxhi + v12 * wxlo;
        float qq = v21 * wxhi + v22 * wxlo;
        lmax = fmaxf(lmax, p * wyhi + qq * wylo);
    };

    stage(0, 0);
    stage(1, 1);

    int t = 0;
    for (; t + 2 < CPW; t += 2) {
        asm volatile("s_waitcnt vmcnt(4)" ::: "memory");  // stage(t) drained
        if (active) compute(rp0);
        asm volatile("s_waitcnt lgkmcnt(0)" ::: "memory"); // ds_reads done before overwrite
        stage(t + 2, 0);
        asm volatile("s_waitcnt vmcnt(4)" ::: "memory");  // stage(t+1) drained
        if (active) compute(rp1);
        asm volatile("s_waitcnt lgkmcnt(0)" ::: "memory");
        stage(t + 3, 1);
    }
    // t == CPW-2
    asm volatile("s_waitcnt vmcnt(4)" ::: "memory");
    if (active) compute(rp0);
    asm volatile("s_waitcnt vmcnt(0)" ::: "memory");
    if (active) compute(rp1);

    // Reduce the 4 sample points (j,i) per bin n within the wave.
    float v = lmax;
    v = fmaxf(v, __shfl_xor(v, 1));
    v = fmaxf(v, __shfl_xor(v, 2));
    if (active && (lane & 3) == 0) pmax[w][n] = v;
    __syncthreads();
    if (tid < MM) {
        float vv = fmaxf(fmaxf(pmax[0][tid], pmax[1][tid]),
                         fmaxf(pmax[2][tid], pmax[3][tid]));
        atomicMaxF(&binmax[m * MM + tid], vv);
    }
}

__global__ __launch_bounds__(256) void roi_bcast(
    const float* __restrict__ binmax, float4* __restrict__ out, int total4)
{
    __shared__ float4 b4[49];  // 196 floats = 49 float4, aligned with bin period
    int t = threadIdx.x;
    if (t < 49) b4[t] = ((const float4*)binmax)[t];
    __syncthreads();
    int idx = blockIdx.x * 256 + t;
    if (idx < total4) out[idx] = b4[idx % 49];
}

extern "C" void kernel_launch(void* const* d_in, const int* in_sizes, int n_in,
                              void* d_out, int out_size, void* d_ws, size_t ws_size,
                              hipStream_t stream) {
    const float* feature = (const float*)d_in[0];
    const float* rois    = (const float*)d_in[1];
    float* binmax = (float*)d_ws;
    float* out    = (float*)d_out;

    const int R = in_sizes[1] / 4;

    roi_init<<<1, 256, 0, stream>>>(binmax);
    roi_reduce<<<R * MM, 256, 0, stream>>>(feature, rois, binmax);

    const int total4 = out_size / 4;
    roi_bcast<<<(total4 + 255) / 256, 256, 0, stream>>>(binmax, (float4*)out, total4);
}

// Round 5
// 163.935 us; speedup vs baseline: 1.0087x; 1.0019x over previous
//
#include <hip/hip_runtime.h>
#include <float.h>

#define CC 256
#define HH 200
#define WW 320
#define HW (HH * WW)
#define MM 14
#define SPAN 152          // padded LDS row length (floats)
#define NB 2              // LDS buffers per wave (double buffer)
#define CG 8              // channel groups == XCD count; cg = bid & 7 pins group->XCD
#define CPB (CC / CG)     // 32 channels per block
#define CPW (CPB / 4)     // 8 channels per wave

typedef __attribute__((address_space(1))) const float GF;
typedef __attribute__((address_space(3))) float LF;

__global__ void roi_init(float* __restrict__ binmax) {
    int t = blockIdx.x * blockDim.x + threadIdx.x;
    if (t < MM * MM) binmax[t] = -FLT_MAX;
}

__device__ inline void atomicMaxF(float* addr, float val) {
    // Ordered-int trick: valid for finite floats starting from -FLT_MAX init.
    if (val >= 0.0f) {
        atomicMax((int*)addr, __float_as_int(val));
    } else {
        atomicMin((unsigned int*)addr, __float_as_uint(val));
    }
}

// One block per (roi, bin-row m, channel-group cg). cg = bid & 7 so the
// round-robin block->XCD dispatch pins each 32-channel slice to one XCD's L2
// (kills cross-XCD fill duplication — R4 measured FETCH 232 MB vs 65.5 MB
// feature). Each wave owns 8 channels end-to-end: DMA-stages its own 4
// feature rows per channel and computes them. NO __syncthreads in the main
// loop — per-wave pipeline with explicit s_waitcnt vmcnt(4).
__global__ __launch_bounds__(256) void roi_reduce(
    const float* __restrict__ feature,
    const float* __restrict__ rois,
    float* __restrict__ binmax)
{
    __shared__ float tile[4][NB][4][SPAN];  // [wave][buf][row][col] = 19,456 B
    __shared__ float pmax[4][MM];

    const int bid = blockIdx.x;
    const int cg  = bid & (CG - 1);
    const int rm  = bid >> 3;
    const int m   = rm % MM;
    const int r   = rm / MM;
    const int tid  = threadIdx.x;
    const int w    = tid >> 6;
    const int lane = tid & 63;
    const int cwave = cg * CPB + w * CPW;   // this wave's first channel

    const float ry1 = rois[r * 4 + 0];
    const float rx1 = rois[r * 4 + 1];
    const float ry2 = rois[r * 4 + 2];
    const float rx2 = rois[r * 4 + 3];
    const float sh = (ry2 - ry1) * (1.0f / 14.0f);
    const float sw = (rx2 - rx1) * (1.0f / 14.0f);
    const float f13 = 1.0f / 3.0f, f23 = 2.0f / 3.0f;

    // Two y sample coords for this bin-row m (reference clamp semantics).
    const float yA = ry1 + sh * (float)m + sh * f13;
    const float yB = ry1 + sh * (float)m + sh * f23;
    const int y1A = min(max((int)floorf(yA), 0), HH - 1);
    const int y2A = min(max((int)floorf(yA) + 1, 0), HH - 1);
    const int y1B = min(max((int)floorf(yB), 0), HH - 1);
    const int y2B = min(max((int)floorf(yB) + 1, 0), HH - 1);
    const float wyloA = yA - (float)y1A, wyhiA = (float)y2A - yA;
    const float wyloB = yB - (float)y1B, wyhiB = (float)y2B - yB;

    // Column window covering all 28 x-sample corners; align base down to x4
    // so global_load_lds dwordx4 addresses are 16B-aligned.
    const float xmin = rx1 + sw * f13;
    const float xmax = rx1 + sw * 13.0f + sw * f23;
    const int xlo = (min(max((int)floorf(xmin), 0), WW - 1)) & ~3;
    const int xhi = min(max((int)floorf(xmax) + 1, 0), WW - 1);
    int span = xhi - xlo + 1;
    if (span > SPAN) span = SPAN;
    const int nlanes = (span + 3) >> 2;    // lanes for width-16 DMA, <= 38

    // Per-lane global pointers for this wave's 4 rows, channel = cwave.
    // Channel stride per pipeline step is HW. Tail lanes may read <=12B past
    // the row's span (pad cols, never read) — page-safe.
    const float* bp0 = feature + (cwave * HW + y1A * WW + xlo) + lane * 4;
    const float* bp1 = feature + (cwave * HW + y2A * WW + xlo) + lane * 4;
    const float* bp2 = feature + (cwave * HW + y1B * WW + xlo) + lane * 4;
    const float* bp3 = feature + (cwave * HW + y2B * WW + xlo) + lane * 4;

    // Compute mapping: lane = n*4 + j*2 + i, lanes 0..55 active.
    const bool active = lane < 56;
    const int n = lane >> 2;
    const int j = (lane >> 1) & 1;
    const int i = lane & 1;

    float wxlo = 0.f, wxhi = 0.f, wylo = 0.f, wyhi = 0.f;
    int o_lane = 0;
    if (active) {
        float x = rx1 + sw * (float)n + sw * (j ? f23 : f13);
        int x1c = min(max((int)floorf(x), 0), WW - 1);
        int x2c = min(max((int)floorf(x) + 1, 0), WW - 1);
        wxlo = x - (float)x1c;
        wxhi = (float)x2c - x;
        int c0 = min(max(x1c - xlo, 0), SPAN - 2);
        int ra = i * 2;                    // rows (0,1) for sample A, (2,3) for B
        o_lane = ra * SPAN + c0;
        if (i == 0) { wylo = wyloA; wyhi = wyhiA; }
        else        { wylo = wyloB; wyhi = wyhiB; }
    }
    const float* rp0 = &tile[w][0][0][0] + o_lane;
    const float* rp1 = &tile[w][1][0][0] + o_lane;

    auto stage = [&](int t, int b) {
        const int co = t * HW;             // channel offset (floats)
        if (lane < nlanes) {
            __builtin_amdgcn_global_load_lds((GF*)(bp0 + co), (LF*)&tile[w][b][0][0], 16, 0, 0);
            __builtin_amdgcn_global_load_lds((GF*)(bp1 + co), (LF*)&tile[w][b][1][0], 16, 0, 0);
            __builtin_amdgcn_global_load_lds((GF*)(bp2 + co), (LF*)&tile[w][b][2][0], 16, 0, 0);
            __builtin_amdgcn_global_load_lds((GF*)(bp3 + co), (LF*)&tile[w][b][3][0], 16, 0, 0);
        }
    };

    float lmax = -FLT_MAX;
    auto compute = [&](const float* rp) {
        float v11 = rp[0];                 // adjacent pairs -> ds_read2_b32
        float v12 = rp[1];
        float v21 = rp[SPAN];
        float v22 = rp[SPAN + 1];
        float p  = v11 * wxhi + v12 * wxlo;
        float qq = v21 * wxhi + v22 * wxlo;
        lmax = fmaxf(lmax, p * wyhi + qq * wylo);
    };

    stage(0, 0);
    stage(1, 1);

    int t = 0;
    for (; t + 2 < CPW; t += 2) {
        asm volatile("s_waitcnt vmcnt(4)" ::: "memory");  // stage(t) drained
        if (active) compute(rp0);
        asm volatile("s_waitcnt lgkmcnt(0)" ::: "memory"); // ds_reads done before overwrite
        stage(t + 2, 0);
        asm volatile("s_waitcnt vmcnt(4)" ::: "memory");  // stage(t+1) drained
        if (active) compute(rp1);
        asm volatile("s_waitcnt lgkmcnt(0)" ::: "memory");
        stage(t + 3, 1);
    }
    // t == CPW-2
    asm volatile("s_waitcnt vmcnt(4)" ::: "memory");
    if (active) compute(rp0);
    asm volatile("s_waitcnt vmcnt(0)" ::: "memory");
    if (active) compute(rp1);

    // Reduce the 4 sample points (j,i) per bin n within the wave.
    float v = lmax;
    v = fmaxf(v, __shfl_xor(v, 1));
    v = fmaxf(v, __shfl_xor(v, 2));
    if (active && (lane & 3) == 0) pmax[w][n] = v;
    __syncthreads();
    if (tid < MM) {
        float vv = fmaxf(fmaxf(pmax[0][tid], pmax[1][tid]),
                         fmaxf(pmax[2][tid], pmax[3][tid]));
        atomicMaxF(&binmax[m * MM + tid], vv);
    }
}

__global__ __launch_bounds__(256) void roi_bcast(
    const float* __restrict__ binmax, float4* __restrict__ out, int total4)
{
    __shared__ float4 b4[49];  // 196 floats = 49 float4, aligned with bin period
    int t = threadIdx.x;
    if (t < 49) b4[t] = ((const float4*)binmax)[t];
    __syncthreads();
    int idx = blockIdx.x * 256 + t;
    if (idx < total4) out[idx] = b4[idx % 49];
}

extern "C" void kernel_launch(void* const* d_in, const int* in_sizes, int n_in,
                              void* d_out, int out_size, void* d_ws, size_t ws_size,
                              hipStream_t stream) {
    const float* feature = (const float*)d_in[0];
    const float* rois    = (const float*)d_in[1];
    float* binmax = (float*)d_ws;
    float* out    = (float*)d_out;

    const int R = in_sizes[1] / 4;

    roi_init<<<1, 256, 0, stream>>>(binmax);
    roi_reduce<<<R * MM * CG, 256, 0, stream>>>(feature, rois, binmax);

    const int total4 = out_size / 4;
    roi_bcast<<<(total4 + 255) / 256, 256, 0, stream>>>(binmax, (float4*)out, total4);
}

// Round 6
// 152.473 us; speedup vs baseline: 1.0845x; 1.0752x over previous
//
#include <hip/hip_runtime.h>
#include <float.h>

#define CC 256
#define HH 200
#define WW 320
#define HW (HH * WW)
#define MM 14
#define CG 8              // channel groups == XCD count; cg = bid & 7 pins group->XCD
#define CPB (CC / CG)     // 32 channels per block
#define CPW (CPB / 4)     // 8 channels per wave

__global__ void roi_init(float* __restrict__ binmax) {
    int t = blockIdx.x * blockDim.x + threadIdx.x;
    if (t < MM * MM) binmax[t] = -FLT_MAX;
}

__device__ inline void atomicMaxF(float* addr, float val) {
    // Ordered-int trick: valid for finite floats starting from -FLT_MAX init.
    if (val >= 0.0f) {
        atomicMax((int*)addr, __float_as_int(val));
    } else {
        atomicMin((unsigned int*)addr, __float_as_uint(val));
    }
}

// One block per (roi, bin-row m, channel-group cg); cg = bid & 7 pins each
// 32-channel slice to one XCD's L2 (R5: FETCH 232 -> 48 MB). NO LDS staging:
// R3-R5 showed global_load_lds is instruction-rate-bound (~25 cyc/inst at
// ~300 B/inst). Each lane gathers its own 4 bilinear corners directly to
// registers; 32 independent loads in flight per wave; zero barriers in the
// main loop. Lane map: lane = i*32 + n*2 + j (56 of 64 lanes active).
__global__ __launch_bounds__(256) void roi_reduce(
    const float* __restrict__ feature,
    const float* __restrict__ rois,
    float* __restrict__ binmax)
{
    __shared__ float pmax[4][MM];

    const int bid = blockIdx.x;
    const int cg  = bid & (CG - 1);
    const int rm  = bid >> 3;
    const int m   = rm % MM;
    const int r   = rm / MM;
    const int tid  = threadIdx.x;
    const int w    = tid >> 6;
    const int lane = tid & 63;

    const float ry1 = rois[r * 4 + 0];
    const float rx1 = rois[r * 4 + 1];
    const float ry2 = rois[r * 4 + 2];
    const float rx2 = rois[r * 4 + 3];
    const float sh = (ry2 - ry1) * (1.0f / 14.0f);
    const float sw = (rx2 - rx1) * (1.0f / 14.0f);
    const float f13 = 1.0f / 3.0f, f23 = 2.0f / 3.0f;

    // Per-lane sample point (n, j, i); lanes with (lane&31) >= 28 idle.
    const int s = lane & 31;
    const int i = lane >> 5;
    const int n = s >> 1;
    const int j = s & 1;
    const bool active = s < 28;

    // Reference semantics exactly: clamp corner indices first, then weights
    // from the clamped corners (edge cases incl. x2==x1 fall out correctly).
    const float x = rx1 + sw * (float)n + sw * (j ? f23 : f13);
    const float y = ry1 + sh * (float)m + sh * (i ? f23 : f13);
    const int x1c = min(max((int)floorf(x), 0), WW - 1);
    const int x2c = min(max((int)floorf(x) + 1, 0), WW - 1);
    const int y1c = min(max((int)floorf(y), 0), HH - 1);
    const int y2c = min(max((int)floorf(y) + 1, 0), HH - 1);
    const float wxlo = x - (float)x1c, wxhi = (float)x2c - x;
    const float wylo = y - (float)y1c, wyhi = (float)y2c - y;

    // Per-lane element offsets within a channel plane (voffset form; channel
    // stepping is a uniform SGPR base advance).
    int o11 = y1c * WW + x1c;
    int o12 = y1c * WW + x2c;
    int o21 = y2c * WW + x1c;
    int o22 = y2c * WW + x2c;
    if (!active) { o11 = o12 = o21 = o22 = 0; }

    const float* fbase = feature + (cg * CPB + w * CPW) * HW;

    // Issue all 32 gathers, then consume in order (compiler staggers vmcnt).
    float v11[CPW], v12[CPW], v21[CPW], v22[CPW];
    #pragma unroll
    for (int c = 0; c < CPW; ++c) {
        const float* fc = fbase + c * HW;
        v11[c] = fc[o11];
        v12[c] = fc[o12];
        v21[c] = fc[o21];
        v22[c] = fc[o22];
    }

    float lmax = -FLT_MAX;
    #pragma unroll
    for (int c = 0; c < CPW; ++c) {
        float p = v11[c] * wxhi + v12[c] * wxlo;
        float q = v21[c] * wxhi + v22[c] * wxlo;
        lmax = fmaxf(lmax, p * wyhi + q * wylo);
    }

    // Reduce over j (xor 1) and i (xor 32); then lanes j==0, n<14 hold bin n.
    float v = lmax;
    v = fmaxf(v, __shfl_xor(v, 1));
    v = fmaxf(v, __shfl_xor(v, 32));
    if (active && j == 0 && i == 0) pmax[w][n] = v;
    __syncthreads();
    if (tid < MM) {
        float vv = fmaxf(fmaxf(pmax[0][tid], pmax[1][tid]),
                         fmaxf(pmax[2][tid], pmax[3][tid]));
        atomicMaxF(&binmax[m * MM + tid], vv);
    }
}

// Grid-stride broadcast with stride 784*256 = 200704 = 49*4096: idx % 49 is
// loop-invariant, so each thread does one cached read + 8 coalesced stores.
#define BCAST_BLOCKS 784
__global__ __launch_bounds__(256) void roi_bcast(
    const float* __restrict__ binmax, float4* __restrict__ out, int total4)
{
    const int idx0 = blockIdx.x * 256 + threadIdx.x;
    const float4 val = ((const float4*)binmax)[idx0 % 49];
    const int stride = BCAST_BLOCKS * 256;
    #pragma unroll
    for (int k = 0; k < 8; ++k) {
        int idx = idx0 + k * stride;
        if (idx < total4) out[idx] = val;
    }
}

extern "C" void kernel_launch(void* const* d_in, const int* in_sizes, int n_in,
                              void* d_out, int out_size, void* d_ws, size_t ws_size,
                              hipStream_t stream) {
    const float* feature = (const float*)d_in[0];
    const float* rois    = (const float*)d_in[1];
    float* binmax = (float*)d_ws;
    float* out    = (float*)d_out;

    const int R = in_sizes[1] / 4;

    roi_init<<<1, 256, 0, stream>>>(binmax);
    roi_reduce<<<R * MM * CG, 256, 0, stream>>>(feature, rois, binmax);

    const int total4 = out_size / 4;
    roi_bcast<<<BCAST_BLOCKS, 256, 0, stream>>>(binmax, (float4*)out, total4);
}

// Round 7
// 148.694 us; speedup vs baseline: 1.1121x; 1.0254x over previous
//
#include <hip/hip_runtime.h>
#include <float.h>

#define CC 256
#define HH 200
#define WW 320
#define HW (HH * WW)
#define MM 14
#define CG 8              // channel groups == XCD count; cg = bid & 7 pins slice->XCD
#define CPB (CC / CG)     // 32 channels per block (fallback kernel)
#define CPW (CPB / 4)     // 8 channels per wave (fallback kernel)

#define WS_FT_OFF 1024
#define FT_BYTES ((size_t)HW * CC * 4)

__global__ void roi_init(float* __restrict__ binmax) {
    int t = blockIdx.x * blockDim.x + threadIdx.x;
    if (t < MM * MM) binmax[t] = -FLT_MAX;
}

__device__ inline void atomicMaxF(float* addr, float val) {
    // Ordered-int trick: valid for finite floats starting from -FLT_MAX init.
    if (val >= 0.0f) {
        atomicMax((int*)addr, __float_as_int(val));
    } else {
        atomicMin((unsigned int*)addr, __float_as_uint(val));
    }
}

// [C,H,W] -> [H,W,C] tiled transpose. Grid: 200 * (320/64) * (256/64) = 4000.
// HBM-bound (~131 MB r+w). Enables dense channel-vector gathers in the reduce.
__global__ __launch_bounds__(256) void roi_transpose(
    const float* __restrict__ f, float* __restrict__ ft)
{
    __shared__ float tile[64][65];
    const int gb = blockIdx.x;
    const int h  = gb / 20;
    const int rest = gb % 20;
    const int wb = (rest / 4) * 64;
    const int cb = (rest % 4) * 64;
    const int tx = threadIdx.x & 63;
    const int g  = threadIdx.x >> 6;
    #pragma unroll
    for (int k = 0; k < 16; ++k) {
        int cl = g * 16 + k;
        tile[cl][tx] = f[(cb + cl) * HW + h * WW + wb + tx];  // coalesced in W
    }
    __syncthreads();
    #pragma unroll
    for (int k = 0; k < 16; ++k) {
        int wl = g * 16 + k;
        ft[(h * WW + wb + wl) * CC + cb + tx] = tile[tx][wl]; // coalesced in C
    }
}

// Transposed-layout reduce. Block = (roi r, channel-group cg); cg = bid & 7
// pins each 32-channel slice to one XCD (R5-proven FETCH dedup). Waves loop
// over all 14 bin-rows m. Lane map: lane = s8*8 + c8 — 8 samples x 8 float4
// channel-quads per wave-gather, so every global_load_dwordx4 instruction
// moves 1 KB of fully-used, 8-segment-contiguous bytes (R6 showed scattered
// 4 B gathers are TA-rate-bound at ~16 cyc/inst regardless of cache hits).
// Wave w: i = w&1 (y sample), n in [(w>>1)*7, +7). Two passes cover 14
// (n,j) samples. Zero barriers until the block tail.
__global__ __launch_bounds__(256) void roi_reduce_t(
    const float* __restrict__ ft,
    const float* __restrict__ rois,
    float* __restrict__ binmax)
{
    __shared__ float pm[MM][MM][2];   // [m][n][i], single writer per cell

    const int bid = blockIdx.x;       // 128 r * 8 cg = 1024
    const int cg  = bid & (CG - 1);
    const int r   = bid >> 3;
    const int tid  = threadIdx.x;
    const int w    = tid >> 6;
    const int lane = tid & 63;
    const int iw    = w & 1;
    const int nbase = (w >> 1) * 7;
    const int s8 = lane >> 3;
    const int c8 = lane & 7;
    const int cgo = cg * 8 + c8;      // float4 offset inside a (y,x) cell

    const float ry1 = rois[r * 4 + 0];
    const float rx1 = rois[r * 4 + 1];
    const float ry2 = rois[r * 4 + 2];
    const float rx2 = rois[r * 4 + 3];
    const float sh = (ry2 - ry1) * (1.0f / 14.0f);
    const float sw = (rx2 - rx1) * (1.0f / 14.0f);
    const float f13 = 1.0f / 3.0f, f23 = 2.0f / 3.0f;
    const float yfrac = iw ? f23 : f13;

    const float4* f4 = (const float4*)ft;

    // Per-lane x geometry for both passes (reference clamp semantics:
    // clamp corner indices first, weights from clamped corners).
    float wxlo[2], wxhi[2];
    int ox1[2], ox2[2];
    bool val[2];
    #pragma unroll
    for (int p = 0; p < 2; ++p) {
        const int ls = p * 8 + s8;
        val[p] = ls < 14;
        const int n = nbase + (ls >> 1);
        const int j = ls & 1;
        const float x = rx1 + sw * (float)n + sw * (j ? f23 : f13);
        const int x1c = min(max((int)floorf(x), 0), WW - 1);
        const int x2c = min(max((int)floorf(x) + 1, 0), WW - 1);
        wxlo[p] = x - (float)x1c;
        wxhi[p] = (float)x2c - x;
        ox1[p] = val[p] ? x1c : 0;
        ox2[p] = val[p] ? x2c : 0;
    }

    for (int m = 0; m < MM; ++m) {
        const float y = ry1 + sh * (float)m + sh * yfrac;
        const int y1c = min(max((int)floorf(y), 0), HH - 1);
        const int y2c = min(max((int)floorf(y) + 1, 0), HH - 1);
        const float wylo = y - (float)y1c, wyhi = (float)y2c - y;
        const int row1 = y1c * WW, row2 = y2c * WW;

        float4 v11[2], v12[2], v21[2], v22[2];
        #pragma unroll
        for (int p = 0; p < 2; ++p) {
            v11[p] = f4[(row1 + ox1[p]) * 64 + cgo];
            v12[p] = f4[(row1 + ox2[p]) * 64 + cgo];
            v21[p] = f4[(row2 + ox1[p]) * 64 + cgo];
            v22[p] = f4[(row2 + ox2[p]) * 64 + cgo];
        }
        #pragma unroll
        for (int p = 0; p < 2; ++p) {
            float px = v11[p].x * wxhi[p] + v12[p].x * wxlo[p];
            float py = v11[p].y * wxhi[p] + v12[p].y * wxlo[p];
            float pz = v11[p].z * wxhi[p] + v12[p].z * wxlo[p];
            float pw = v11[p].w * wxhi[p] + v12[p].w * wxlo[p];
            float qx = v21[p].x * wxhi[p] + v22[p].x * wxlo[p];
            float qy = v21[p].y * wxhi[p] + v22[p].y * wxlo[p];
            float qz = v21[p].z * wxhi[p] + v22[p].z * wxlo[p];
            float qw = v21[p].w * wxhi[p] + v22[p].w * wxlo[p];
            float rx = px * wyhi + qx * wylo;
            float ry = py * wyhi + qy * wylo;
            float rz = pz * wyhi + qz * wylo;
            float rw = pw * wyhi + qw * wylo;
            float sm = fmaxf(fmaxf(rx, ry), fmaxf(rz, rw));
            if (!val[p]) sm = -FLT_MAX;
            // reduce over c8 (xor 1,2,4) then over j (xor 8)
            sm = fmaxf(sm, __shfl_xor(sm, 1));
            sm = fmaxf(sm, __shfl_xor(sm, 2));
            sm = fmaxf(sm, __shfl_xor(sm, 4));
            sm = fmaxf(sm, __shfl_xor(sm, 8));
            const int ls = p * 8 + s8;
            if ((lane & 15) == 0 && val[p])
                pm[m][nbase + (ls >> 1)][iw] = sm;
        }
    }

    __syncthreads();
    if (tid < MM * MM) {
        float vv = fmaxf(pm[tid / MM][tid % MM][0], pm[tid / MM][tid % MM][1]);
        atomicMaxF(&binmax[tid], vv);
    }
}

// ---------- fallback (R6 gather) if ws can't hold the transposed feature ----
__global__ __launch_bounds__(256) void roi_reduce_g(
    const float* __restrict__ feature,
    const float* __restrict__ rois,
    float* __restrict__ binmax)
{
    __shared__ float pmax[4][MM];
    const int bid = blockIdx.x;
    const int cg  = bid & (CG - 1);
    const int rm  = bid >> 3;
    const int m   = rm % MM;
    const int r   = rm / MM;
    const int tid  = threadIdx.x;
    const int w    = tid >> 6;
    const int lane = tid & 63;

    const float ry1 = rois[r * 4 + 0];
    const float rx1 = rois[r * 4 + 1];
    const float ry2 = rois[r * 4 + 2];
    const float rx2 = rois[r * 4 + 3];
    const float sh = (ry2 - ry1) * (1.0f / 14.0f);
    const float sw = (rx2 - rx1) * (1.0f / 14.0f);
    const float f13 = 1.0f / 3.0f, f23 = 2.0f / 3.0f;

    const int s = lane & 31;
    const int i = lane >> 5;
    const int n = s >> 1;
    const int j = s & 1;
    const bool active = s < 28;

    const float x = rx1 + sw * (float)n + sw * (j ? f23 : f13);
    const float y = ry1 + sh * (float)m + sh * (i ? f23 : f13);
    const int x1c = min(max((int)floorf(x), 0), WW - 1);
    const int x2c = min(max((int)floorf(x) + 1, 0), WW - 1);
    const int y1c = min(max((int)floorf(y), 0), HH - 1);
    const int y2c = min(max((int)floorf(y) + 1, 0), HH - 1);
    const float wxlo = x - (float)x1c, wxhi = (float)x2c - x;
    const float wylo = y - (float)y1c, wyhi = (float)y2c - y;

    int o11 = y1c * WW + x1c, o12 = y1c * WW + x2c;
    int o21 = y2c * WW + x1c, o22 = y2c * WW + x2c;
    if (!active) { o11 = o12 = o21 = o22 = 0; }

    const float* fbase = feature + (cg * CPB + w * CPW) * HW;
    float v11[CPW], v12[CPW], v21[CPW], v22[CPW];
    #pragma unroll
    for (int c = 0; c < CPW; ++c) {
        const float* fc = fbase + c * HW;
        v11[c] = fc[o11]; v12[c] = fc[o12]; v21[c] = fc[o21]; v22[c] = fc[o22];
    }
    float lmax = -FLT_MAX;
    #pragma unroll
    for (int c = 0; c < CPW; ++c) {
        float p = v11[c] * wxhi + v12[c] * wxlo;
        float q = v21[c] * wxhi + v22[c] * wxlo;
        lmax = fmaxf(lmax, p * wyhi + q * wylo);
    }
    float v = lmax;
    v = fmaxf(v, __shfl_xor(v, 1));
    v = fmaxf(v, __shfl_xor(v, 32));
    if (active && j == 0 && i == 0) pmax[w][n] = v;
    __syncthreads();
    if (tid < MM) {
        float vv = fmaxf(fmaxf(pmax[0][tid], pmax[1][tid]),
                         fmaxf(pmax[2][tid], pmax[3][tid]));
        atomicMaxF(&binmax[m * MM + tid], vv);
    }
}

#define BCAST_BLOCKS 784
__global__ __launch_bounds__(256) void roi_bcast(
    const float* __restrict__ binmax, float4* __restrict__ out, int total4)
{
    const int idx0 = blockIdx.x * 256 + threadIdx.x;
    const float4 val = ((const float4*)binmax)[idx0 % 49];
    const int stride = BCAST_BLOCKS * 256;
    #pragma unroll
    for (int k = 0; k < 8; ++k) {
        int idx = idx0 + k * stride;
        if (idx < total4) out[idx] = val;
    }
}

extern "C" void kernel_launch(void* const* d_in, const int* in_sizes, int n_in,
                              void* d_out, int out_size, void* d_ws, size_t ws_size,
                              hipStream_t stream) {
    const float* feature = (const float*)d_in[0];
    const float* rois    = (const float*)d_in[1];
    float* binmax = (float*)d_ws;
    float* out    = (float*)d_out;

    const int R = in_sizes[1] / 4;

    roi_init<<<1, 256, 0, stream>>>(binmax);

    if (ws_size >= WS_FT_OFF + FT_BYTES) {
        float* ft = (float*)((char*)d_ws + WS_FT_OFF);
        roi_transpose<<<HH * (WW / 64) * (CC / 64), 256, 0, stream>>>(feature, ft);
        roi_reduce_t<<<R * CG, 256, 0, stream>>>(ft, rois, binmax);
    } else {
        roi_reduce_g<<<R * MM * CG, 256, 0, stream>>>(feature, rois, binmax);
    }

    const int total4 = out_size / 4;
    roi_bcast<<<BCAST_BLOCKS, 256, 0, stream>>>(binmax, (float4*)out, total4);
}